// Round 2
// 254.276 us; speedup vs baseline: 1.0293x; 1.0293x over previous
//
#include <hip/hip_runtime.h>

// Rotation by label: B=256, C=3, H=W=224 fp32.
//   lab 0: out[h][w] = in[h][w]
//   lab 1: out[h][w] = in[w][h]            (transpose)
//   lab 2: out[h][w] = in[223-h][w]        (flip rows)
//   lab 3: out[h][w] = in[223-w][h]        (transpose + flip cols)
//
// v2b: identical to v2 but uses a clang ext_vector float4 (f4) for the
// nontemporal builtins -- HIP's float4 is a class type and is rejected by
// __builtin_nontemporal_{load,store}.
//
// Design:
//   - one block per 32-row band (b,c,th) -> 7 float4/thread
//   - lab 0: band is one contiguous 28 KB region -> pure linear f4 copy
//   - lab 2: write side fully linear; read rows reversed (whole contiguous rows)
//   - lab 1/3: 7x 32x32 LDS tile transposes, double-buffered, next tile's
//     global load issued BEFORE __syncthreads (latency overlap)
//   - nontemporal loads/stores (pure streaming, zero reuse)
//   - label write fused into the first blocks (drops second launch)
// Label is uniform per block (depends only on b) -> no divergence.

#define HW 224
#define W4 56        // HW/4 float4 per row
#define TILE 32
#define NT 7         // 224 / 32

typedef float f4 __attribute__((ext_vector_type(4)));

__global__ __launch_bounds__(256) void rot4_kernel(const float* __restrict__ x,
                                                   const int* __restrict__ label,
                                                   float* __restrict__ out,
                                                   float* __restrict__ out_label,
                                                   int B) {
    const int t = threadIdx.x;

    // fused label write (second tuple element, as float)
    {
        int li = blockIdx.x * 256 + t;
        if (blockIdx.x < (B + 255) / 256 && li < B) out_label[li] = (float)label[li];
    }

    int blk = blockIdx.x;
    const int th = blk % NT; blk /= NT;    // band index (32 rows)
    const int c  = blk % 3;  blk /= 3;     // channel
    const int b  = blk;                    // batch

    const int lab = label[b];              // block-uniform
    const size_t plane = (size_t)(b * 3 + c) * (HW * HW);
    const float*  in = x + plane;
    float*        o  = out + plane;
    const f4* in4 = (const f4*)in;
    f4*       o4  = (f4*)o;
    const int h0 = th * TILE;

    if (lab == 0) {
        // band [h0, h0+32) is one contiguous run of 7*256 f4
        const size_t base = (size_t)h0 * W4;
        #pragma unroll
        for (int k = 0; k < NT; ++k) {
            size_t i = base + (size_t)k * 256 + t;
            f4 v = __builtin_nontemporal_load(in4 + i);
            __builtin_nontemporal_store(v, o4 + i);
        }
    } else if (lab == 2) {
        // out row h = in row 223-h; write side linear over the band
        #pragma unroll
        for (int k = 0; k < NT; ++k) {
            int idx = k * 256 + t;         // 0..1791 within band
            int rr  = idx / W4;            // row within band (0..31)
            int cc  = idx - rr * W4;       // float4 col (0..55)
            size_t src = (size_t)(HW - 1 - (h0 + rr)) * W4 + cc;
            size_t dst = (size_t)(h0 + rr) * W4 + cc;
            f4 v = __builtin_nontemporal_load(in4 + src);
            __builtin_nontemporal_store(v, o4 + dst);
        }
    } else {
        // transpose via LDS tiles; stride 33 -> <=2-way bank aliasing (free on wave64)
        // double-buffered so a single __syncthreads per tile suffices, and the
        // next tile's global load is issued before the sync.
        __shared__ float tb[2][TILE][TILE + 1];
        const int r  = t >> 3;             // 0..31 tile row
        const int c4 = t & 7;              // 0..7  float4 col within tile

        // source tile rows: lab==1 -> [w0, w0+32); lab==3 -> [192-w0, 224-w0)
        auto src_ptr = [&](int tw) {
            const int w0 = tw * TILE;
            const int rbase = (lab == 1) ? w0 : (HW - TILE - w0);
            return (const f4*)(in + (size_t)(rbase + r) * HW + h0 + c4 * 4);
        };

        f4 v = __builtin_nontemporal_load(src_ptr(0));
        #pragma unroll
        for (int tw = 0; tw < NT; ++tw) {
            float (*tbuf)[TILE + 1] = tb[tw & 1];
            tbuf[r][c4 * 4 + 0] = v.x;
            tbuf[r][c4 * 4 + 1] = v.y;
            tbuf[r][c4 * 4 + 2] = v.z;
            tbuf[r][c4 * 4 + 3] = v.w;
            if (tw + 1 < NT)  // issue next tile's load before the barrier
                v = __builtin_nontemporal_load(src_ptr(tw + 1));
            __syncthreads();
            f4 w;
            if (lab == 1) {
                // out[h0+r][w0+4c4+j] = in[w0+4c4+j][h0+r] = tbuf[4c4+j][r]
                w.x = tbuf[c4 * 4 + 0][r];
                w.y = tbuf[c4 * 4 + 1][r];
                w.z = tbuf[c4 * 4 + 2][r];
                w.w = tbuf[c4 * 4 + 3][r];
            } else {
                // out[h0+r][w0+4c4+j] = in[223-w0-4c4-j][h0+r] = tbuf[31-4c4-j][r]
                w.x = tbuf[31 - (c4 * 4 + 0)][r];
                w.y = tbuf[31 - (c4 * 4 + 1)][r];
                w.z = tbuf[31 - (c4 * 4 + 2)][r];
                w.w = tbuf[31 - (c4 * 4 + 3)][r];
            }
            const int w0 = tw * TILE;
            __builtin_nontemporal_store(
                w, (f4*)(o + (size_t)(h0 + r) * HW + w0 + c4 * 4));
        }
    }
}

extern "C" void kernel_launch(void* const* d_in, const int* in_sizes, int n_in,
                              void* d_out, int out_size, void* d_ws, size_t ws_size,
                              hipStream_t stream) {
    const float* x     = (const float*)d_in[0];
    const int*   label = (const int*)d_in[1];
    float*       out   = (float*)d_out;

    const int B = in_sizes[1];                       // 256
    const int nblocks = B * 3 * NT;                  // one block per 32-row band
    const size_t img_elems = (size_t)B * 3 * HW * HW;

    rot4_kernel<<<nblocks, 256, 0, stream>>>(x, label, out, out + img_elems, B);
}

// Round 3
// 250.177 us; speedup vs baseline: 1.0462x; 1.0164x over previous
//
#include <hip/hip_runtime.h>

// Rotation by label: B=256, C=3, H=W=224 fp32.
//   lab 0: out[h][w] = in[h][w]
//   lab 1: out[h][w] = in[w][h]            (transpose)
//   lab 2: out[h][w] = in[223-h][w]        (flip rows)
//   lab 3: out[h][w] = in[223-w][h]        (transpose + flip cols)
//
// v3: v2b + full register prefetch in the transpose path.
//   The lab 1/3 path previously had only 2 global loads in flight per thread
//   (load -> LDS -> barrier -> read -> store serialization); the copy paths
//   have MLP 7. Now all 7 tile loads (7 x f4 = 28 VGPR) issue up-front, then
//   the double-buffered LDS transpose loop consumes them with one barrier per
//   tile. Copy paths unchanged (already linear, MLP 7, nontemporal).
// Label is uniform per block (depends only on b) -> no divergence.

#define HW 224
#define W4 56        // HW/4 float4 per row
#define TILE 32
#define NT 7         // 224 / 32

typedef float f4 __attribute__((ext_vector_type(4)));

__global__ __launch_bounds__(256) void rot4_kernel(const float* __restrict__ x,
                                                   const int* __restrict__ label,
                                                   float* __restrict__ out,
                                                   float* __restrict__ out_label,
                                                   int B) {
    const int t = threadIdx.x;

    // fused label write (second tuple element, as float)
    {
        int li = blockIdx.x * 256 + t;
        if (blockIdx.x < (B + 255) / 256 && li < B) out_label[li] = (float)label[li];
    }

    int blk = blockIdx.x;
    const int th = blk % NT; blk /= NT;    // band index (32 rows)
    const int c  = blk % 3;  blk /= 3;     // channel
    const int b  = blk;                    // batch

    const int lab = label[b];              // block-uniform
    const size_t plane = (size_t)(b * 3 + c) * (HW * HW);
    const float*  in = x + plane;
    float*        o  = out + plane;
    const f4* in4 = (const f4*)in;
    f4*       o4  = (f4*)o;
    const int h0 = th * TILE;

    if (lab == 0) {
        // band [h0, h0+32) is one contiguous run of 7*256 f4
        const size_t base = (size_t)h0 * W4;
        #pragma unroll
        for (int k = 0; k < NT; ++k) {
            size_t i = base + (size_t)k * 256 + t;
            f4 v = __builtin_nontemporal_load(in4 + i);
            __builtin_nontemporal_store(v, o4 + i);
        }
    } else if (lab == 2) {
        // out row h = in row 223-h; write side linear over the band
        #pragma unroll
        for (int k = 0; k < NT; ++k) {
            int idx = k * 256 + t;         // 0..1791 within band
            int rr  = idx / W4;            // row within band (0..31)
            int cc  = idx - rr * W4;       // float4 col (0..55)
            size_t src = (size_t)(HW - 1 - (h0 + rr)) * W4 + cc;
            size_t dst = (size_t)(h0 + rr) * W4 + cc;
            f4 v = __builtin_nontemporal_load(in4 + src);
            __builtin_nontemporal_store(v, o4 + dst);
        }
    } else {
        // transpose via LDS tiles; stride 33 -> <=2-way bank aliasing (free on wave64)
        // double-buffered (1 barrier per tile); ALL 7 tile loads prefetched to
        // registers before the loop for maximum memory-level parallelism.
        __shared__ float tb[2][TILE][TILE + 1];
        const int r  = t >> 3;             // 0..31 tile row
        const int c4 = t & 7;              // 0..7  float4 col within tile

        // source tile rows: lab==1 -> [w0, w0+32); lab==3 -> [192-w0, 224-w0)
        auto src_ptr = [&](int tw) {
            const int w0 = tw * TILE;
            const int rbase = (lab == 1) ? w0 : (HW - TILE - w0);
            return (const f4*)(in + (size_t)(rbase + r) * HW + h0 + c4 * 4);
        };

        f4 v[NT];
        #pragma unroll
        for (int k = 0; k < NT; ++k)
            v[k] = __builtin_nontemporal_load(src_ptr(k));

        #pragma unroll
        for (int tw = 0; tw < NT; ++tw) {
            float (*tbuf)[TILE + 1] = tb[tw & 1];
            tbuf[r][c4 * 4 + 0] = v[tw].x;
            tbuf[r][c4 * 4 + 1] = v[tw].y;
            tbuf[r][c4 * 4 + 2] = v[tw].z;
            tbuf[r][c4 * 4 + 3] = v[tw].w;
            __syncthreads();
            f4 w;
            if (lab == 1) {
                // out[h0+r][w0+4c4+j] = in[w0+4c4+j][h0+r] = tbuf[4c4+j][r]
                w.x = tbuf[c4 * 4 + 0][r];
                w.y = tbuf[c4 * 4 + 1][r];
                w.z = tbuf[c4 * 4 + 2][r];
                w.w = tbuf[c4 * 4 + 3][r];
            } else {
                // out[h0+r][w0+4c4+j] = in[223-w0-4c4-j][h0+r] = tbuf[31-4c4-j][r]
                w.x = tbuf[31 - (c4 * 4 + 0)][r];
                w.y = tbuf[31 - (c4 * 4 + 1)][r];
                w.z = tbuf[31 - (c4 * 4 + 2)][r];
                w.w = tbuf[31 - (c4 * 4 + 3)][r];
            }
            const int w0 = tw * TILE;
            __builtin_nontemporal_store(
                w, (f4*)(o + (size_t)(h0 + r) * HW + w0 + c4 * 4));
        }
    }
}

extern "C" void kernel_launch(void* const* d_in, const int* in_sizes, int n_in,
                              void* d_out, int out_size, void* d_ws, size_t ws_size,
                              hipStream_t stream) {
    const float* x     = (const float*)d_in[0];
    const int*   label = (const int*)d_in[1];
    float*       out   = (float*)d_out;

    const int B = in_sizes[1];                       // 256
    const int nblocks = B * 3 * NT;                  // one block per 32-row band
    const size_t img_elems = (size_t)B * 3 * HW * HW;

    rot4_kernel<<<nblocks, 256, 0, stream>>>(x, label, out, out + img_elems, B);
}